// Round 11
// baseline (251.467 us; speedup 1.0000x reference)
//
#include <hip/hip_runtime.h>
#include <hip/hip_bf16.h>

#define KK 5
constexpr int N0 = 78400;     // B*28*28
constexpr int E0 = 627200;    // N0*8
constexpr int N1 = 19600;     // B*14*14
constexpr int E1 = 156800;    // N1*8
constexpr int C1 = 32, C2 = 64;
constexpr int BSZ = 100;
constexpr int FC1_IN = 3136, FC1_OUT = 512;
constexpr int CAP = 48;       // max stored edges per node (Poisson(8) tail ~1e-20)
constexpr int KEXT = 832;     // 800 tap-space + 32 root channels
constexpr int ULS = 836;      // LDS fp32 U row stride: %4==0 (16B align), %32==4 (bank stagger)

typedef __attribute__((ext_vector_type(8))) short bf16x8;
typedef __attribute__((ext_vector_type(4))) float f32x4;

__device__ __forceinline__ unsigned short f2bf(float f) {
    union { float f; unsigned u; } v; v.f = f;
    unsigned u = v.u;
    unsigned r = (u + 0x7FFF + ((u >> 16) & 1)) >> 16;   // RNE
    return (unsigned short)r;
}

__device__ __forceinline__ void taps_of(const float* pseudo, int e,
                                        int& a00, int& a01, int& a10, int& a11,
                                        float& c00, float& c01, float& c10, float& c11) {
    float px = pseudo[2 * e] * (KK - 1);
    float py = pseudo[2 * e + 1] * (KK - 1);
    float kfx = floorf(px), kfy = floorf(py);
    float fx = px - kfx, fy = py - kfy;
    int k0x = min(max((int)kfx, 0), KK - 1);
    int k0y = min(max((int)kfy, 0), KK - 1);
    int k1x = min(k0x + 1, KK - 1), k1y = min(k0y + 1, KK - 1);
    a00 = k0x * KK + k0y; a01 = k0x * KK + k1y;
    a10 = k1x * KK + k0y; a11 = k1x * KK + k1y;
    float gx = 1.f - fx, gy = 1.f - fy;
    c00 = gx * gy; c01 = gx * fy; c10 = fx * gy; c11 = fx * fy;
}

// ---- bucket (both graphs in one launch): one int atomic per edge ----
__global__ void bucket_both(const int* __restrict__ ei0, const int* __restrict__ ei1,
                            int* __restrict__ cnt1, int* __restrict__ rec1,
                            int* __restrict__ cnt2, int* __restrict__ rec2) {
    int gid = blockIdx.x * blockDim.x + threadIdx.x;
    if (gid < E0) {
        int dstn = ei0[E0 + gid];
        int r = atomicAdd(&cnt1[dstn], 1);
        if (r < CAP) rec1[dstn * CAP + r] = gid;
    } else if (gid < E0 + E1) {
        int e = gid - E0;
        int dstn = ei1[E1 + e];
        int r = atomicAdd(&cnt2[dstn], 1);
        if (r < CAP) rec2[dstn * CAP + r] = e;
    }
}

// ---- conv1 fused: 64 nodes/block. Phase1: tap-space S in LDS (4 thr/node).
//      Phase2: h1[n,o] = ELU((S@W1)/deg + x*root + bias). No atomics. ----
__global__ void conv1_fused(const float* __restrict__ x, const float* __restrict__ ps0,
                            const int* __restrict__ ei0, const int* __restrict__ cnt1,
                            const int* __restrict__ rec1, const float* __restrict__ W1,
                            const float* __restrict__ root, const float* __restrict__ bias,
                            float* __restrict__ h1) {
    __shared__ float S4[64][4][25];   // 25.6 KB, thread-private quadrants
    __shared__ float Sr[64][25];      // 6.4 KB, reduced
    int t = threadIdx.x;
    int nb = blockIdx.x * 64;
    {
        int q = t & 3, nl = t >> 2;
        float* sp = &S4[nl][q][0];
#pragma unroll
        for (int a = 0; a < 25; a++) sp[a] = 0.f;
        int m = min(cnt1[nb + nl], CAP);
        const int* rp = rec1 + (nb + nl) * CAP;
        for (int r = q; r < m; r += 4) {
            int e = rp[r];
            int srcn = ei0[e];
            int a00, a01, a10, a11; float c00, c01, c10, c11;
            taps_of(ps0, e, a00, a01, a10, a11, c00, c01, c10, c11);
            float xv = x[srcn];
            sp[a00] += c00 * xv; sp[a01] += c01 * xv;
            sp[a10] += c10 * xv; sp[a11] += c11 * xv;
        }
    }
    __syncthreads();
    for (int idx = t; idx < 64 * 25; idx += 256) {
        int nl = idx / 25, a = idx - nl * 25;
        Sr[nl][a] = S4[nl][0][a] + S4[nl][1][a] + S4[nl][2][a] + S4[nl][3][a];
    }
    __syncthreads();
    int o = t & 31, ng = t >> 5;
    float w1c[25];
#pragma unroll
    for (int a = 0; a < 25; a++) w1c[a] = W1[a * C1 + o];
    float ro = root[o], bo = bias[o];
    for (int j = 0; j < 8; j++) {
        int nl = ng * 8 + j;
        int n = nb + nl;
        float acc = 0.f;
#pragma unroll
        for (int a = 0; a < 25; a++) acc += Sr[nl][a] * w1c[a];
        float v = acc / fmaxf((float)cnt1[n], 1.f) + x[n] * ro + bo;
        h1[n * C1 + o] = v > 0.f ? v : expm1f(v);
    }
}

// ---- pool1: [100,28,28,32] -> [100,14,14,32] ----
__global__ void pool1(const float* __restrict__ h1, float* __restrict__ p1) {
    int idx = blockIdx.x * blockDim.x + threadIdx.x;
    if (idx >= N1 * C1) return;
    int o = idx & 31; int t = idx >> 5;
    int c = t % 14; int r = (t / 14) % 14; int b = t / 196;
    const float* base = h1 + (((b * 28 + 2 * r) * 28 + 2 * c) * C1 + o);
    float m = fmaxf(fmaxf(base[0], base[C1]),
                    fmaxf(base[28 * C1], base[28 * C1 + C1]));
    p1[idx] = m;
}

// ---- w2t prep: bf16 transposed W2ext [64 o][832 k]; k<800 -> W2, else root2 ----
__global__ void w2t_prep(const float* __restrict__ W2, const float* __restrict__ root2,
                         unsigned short* __restrict__ w2t) {
    int idx = blockIdx.x * blockDim.x + threadIdx.x;
    if (idx >= 64 * KEXT) return;
    int o = idx / KEXT, k = idx - o * KEXT;
    float v = (k < 800) ? W2[k * 64 + o] : root2[(k - 800) * 64 + o];
    w2t[idx] = f2bf(v);
}

// ---- wt1 prep: fc1w [3136,512] fp32 -> transposed bf16 wt1[512][3136] ----
__global__ void wt1_prep(const float* __restrict__ w, unsigned short* __restrict__ wt1) {
    __shared__ unsigned short tile[64 * 66];
    int t = threadIdx.x;
    int k0 = blockIdx.x * 64, j0 = blockIdx.y * 64;
    int jj = t & 63, ks = t >> 6;
    for (int kk = ks; kk < 64; kk += 4)
        tile[kk * 66 + jj] = f2bf(w[(k0 + kk) * FC1_OUT + j0 + jj]);
    __syncthreads();
    int kk = t & 63, js = t >> 6;
    for (int j2 = js; j2 < 64; j2 += 4)
        wt1[(j0 + j2) * FC1_IN + k0 + kk] = tile[kk * 66 + j2];
}

// ---- conv2 fused (MFMA): 16 nodes/block, LDS 53.5 KB -> 3 blocks/CU.
//  Phase1: parallel meta prefetch (lane r owns edge slot r / r+32) then
//          shuffle-broadcast accumulation into U[16][832] fp32 in LDS.
//  Phase2: on-the-fly fp32->bf16 A-pack; h2 = ELU(U@w2t^T + b2) via MFMA.
__global__ __launch_bounds__(256, 3)
void conv2_fused(const float* __restrict__ p1, const float* __restrict__ ps1,
                 const int* __restrict__ ei1, const int* __restrict__ cnt2,
                 const int* __restrict__ rec2,
                 const unsigned short* __restrict__ w2t,
                 const float* __restrict__ b2, float* __restrict__ h2) {
    __shared__ float Ul[16 * ULS];          // 53.5 KB
    int t = threadIdx.x;
    int nb = blockIdx.x * 16;
    int i = t & 31, g = t >> 5;             // channel lane, group 0..7
    // zero U rows + load root channels (group-private rows; no barrier needed)
    for (int nn = g; nn < 16; nn += 8) {
        float* up = Ul + nn * ULS;
#pragma unroll
        for (int a = 0; a < 25; a++) up[a * 32 + i] = 0.f;
        up[800 + i] = p1[(nb + nn) * C1 + i];
    }
    // phase 1: per group, 2 nodes. Parallel meta fetch, then shuffle-fed accum.
    for (int nn = g; nn < 16; nn += 8) {
        int n = nb + nn;
        int cnt = cnt2[n];
        int m = min(cnt, CAP);
        float invd = 1.f / fmaxf((float)cnt, 1.f);
        const int* rp = rec2 + n * CAP;
        int srcn0 = 0, pid0 = 0, srcn1 = 0, pid1 = 0;
        float c00_ = 0.f, c01_ = 0.f, c10_ = 0.f, c11_ = 0.f;
        float d00_ = 0.f, d01_ = 0.f, d10_ = 0.f, d11_ = 0.f;
        if (i < m) {
            int e = rp[i];
            srcn0 = ei1[e];
            int a00, a01, a10, a11; float c00, c01, c10, c11;
            taps_of(ps1, e, a00, a01, a10, a11, c00, c01, c10, c11);
            pid0 = a00 | (a01 << 8) | (a10 << 16) | (a11 << 24);
            c00_ = c00 * invd; c01_ = c01 * invd;
            c10_ = c10 * invd; c11_ = c11 * invd;
        }
        if (i + 32 < m) {
            int e = rp[i + 32];
            srcn1 = ei1[e];
            int a00, a01, a10, a11; float c00, c01, c10, c11;
            taps_of(ps1, e, a00, a01, a10, a11, c00, c01, c10, c11);
            pid1 = a00 | (a01 << 8) | (a10 << 16) | (a11 << 24);
            d00_ = c00 * invd; d01_ = c01 * invd;
            d10_ = c10 * invd; d11_ = c11 * invd;
        }
        float* up = Ul + nn * ULS;
#pragma unroll 2
        for (int j = 0; j < m; j++) {
            int jj = j & 31;
            bool hi = j >= 32;
            int src = __shfl(hi ? srcn1 : srcn0, jj, 32);
            int pid = __shfl(hi ? pid1 : pid0, jj, 32);
            float k0 = __shfl(hi ? d00_ : c00_, jj, 32);
            float k1 = __shfl(hi ? d01_ : c01_, jj, 32);
            float k2 = __shfl(hi ? d10_ : c10_, jj, 32);
            float k3 = __shfl(hi ? d11_ : c11_, jj, 32);
            float xv = p1[src * C1 + i];
            up[(pid & 0xff) * 32 + i]         += k0 * xv;
            up[((pid >> 8) & 0xff) * 32 + i]  += k1 * xv;
            up[((pid >> 16) & 0xff) * 32 + i] += k2 * xv;
            up[((pid >> 24) & 0xff) * 32 + i] += k3 * xv;
        }
    }
    __syncthreads();
    // phase 2: MFMA. wave w -> o-tile w. D[node=quad*4+r][o=lane&15]
    int wv = t >> 6, lane = t & 63, quad = lane >> 4, lrow = lane & 15;
    f32x4 acc = {0.f, 0.f, 0.f, 0.f};
    const unsigned short* bbase = w2t + (wv * 16 + lrow) * KEXT;
    const float* abase = Ul + lrow * ULS;
#pragma unroll
    for (int kc = 0; kc < 26; kc++) {
        float4 a0 = *(const float4*)(abase + kc * 32 + quad * 8);
        float4 a1 = *(const float4*)(abase + kc * 32 + quad * 8 + 4);
        bf16x8 a;
        a[0] = (short)f2bf(a0.x); a[1] = (short)f2bf(a0.y);
        a[2] = (short)f2bf(a0.z); a[3] = (short)f2bf(a0.w);
        a[4] = (short)f2bf(a1.x); a[5] = (short)f2bf(a1.y);
        a[6] = (short)f2bf(a1.z); a[7] = (short)f2bf(a1.w);
        bf16x8 b = *(const bf16x8*)(bbase + kc * 32 + quad * 8);
        acc = __builtin_amdgcn_mfma_f32_16x16x32_bf16(a, b, acc, 0, 0, 0);
    }
    int o = wv * 16 + lrow;
    float bo = b2[o];
#pragma unroll
    for (int r = 0; r < 4; r++) {
        int node = quad * 4 + r;
        float v = acc[r] + bo;
        v = v > 0.f ? v : expm1f(v);
        h2[(nb + node) * C2 + o] = v;
    }
}

// ---- pool2 -> bf16 [112 x 3136], rows 100..111 zeroed (M-pad for MFMA) ----
__global__ void pool2b(const float* __restrict__ h2, unsigned short* __restrict__ p2b) {
    int idx = blockIdx.x * blockDim.x + threadIdx.x;
    if (idx >= 112 * FC1_IN) return;
    if (idx >= 100 * FC1_IN) { p2b[idx] = 0; return; }
    int o = idx & 63; int t2 = idx >> 6;
    int c = t2 % 14; int r = (t2 / 14) % 14; int b = t2 / 196;
    const float* base = h2 + (((b * 28 + 2 * r) * 28 + 2 * c) * C2 + o);
    float m = fmaxf(fmaxf(base[0], base[C2]),
                    fmaxf(base[28 * C2], base[28 * C2 + C2]));
    p2b[idx] = f2bf(m);
}

// ---- fc1 MFMA: [112,3136]bf16 @ wt1^T -> z1p fp32 partials (2 kz). ----
__global__ void gemm_fc1(const unsigned short* __restrict__ p2b,
                         const unsigned short* __restrict__ wt1,
                         float* __restrict__ z1p) {
    constexpr int AS = 232;              // 224 + 8 pad, 16B aligned
    __shared__ unsigned short as_[16 * AS];   // 7.4 KB
    int t = threadIdx.x;
    int jt = blockIdx.x, mt = blockIdx.y, kz = blockIdx.z;
    int wv = t >> 6, lane = t & 63, quad = lane >> 4, lrow = lane & 15;
    int m0 = mt * 16;
    int kbase = kz * 1568;
    const unsigned short* bbase = wt1 + (jt * 64 + wv * 16 + lrow) * FC1_IN + kbase;
    f32x4 acc = {0.f, 0.f, 0.f, 0.f};
    for (int ch = 0; ch < 7; ch++) {
        __syncthreads();
        for (int slot = t; slot < 448; slot += 256) {   // 16 rows x 28 uint4
            int r = slot / 28, c = slot - (slot / 28) * 28;
            *(uint4*)(as_ + r * AS + c * 8) =
                *(const uint4*)(p2b + (m0 + r) * FC1_IN + kbase + ch * 224 + c * 8);
        }
        __syncthreads();
        const unsigned short* ab = as_ + lrow * AS;
        const unsigned short* bb = bbase + ch * 224;
#pragma unroll
        for (int kk = 0; kk < 7; kk++) {
            bf16x8 a = *(const bf16x8*)(ab + kk * 32 + quad * 8);
            bf16x8 b = *(const bf16x8*)(bb + kk * 32 + quad * 8);
            acc = __builtin_amdgcn_mfma_f32_16x16x32_bf16(a, b, acc, 0, 0, 0);
        }
    }
    int n = jt * 64 + wv * 16 + lrow;
#pragma unroll
    for (int r = 0; r < 4; r++) {
        int m = m0 + quad * 4 + r;
        z1p[kz * (112 * FC1_OUT) + m * FC1_OUT + n] = acc[r];
    }
}

// ---- fc2 + log_softmax fused; sums 2 fc1 partials, applies fc1 bias+ELU ----
__global__ void fc2_lsm(const float* __restrict__ z1p, const float* __restrict__ fc1b,
                        const float* __restrict__ w, const float* __restrict__ fc2b,
                        float* __restrict__ out) {
    int b = blockIdx.x;
    int t = threadIdx.x;
    int wv = t >> 6;
    int lane = t & 63;
    float acc = 0.f;
#pragma unroll
    for (int m = 0; m < 8; m++) {
        int k = lane * 8 + m;
        float xv = fc1b[k] + z1p[b * FC1_OUT + k] + z1p[112 * FC1_OUT + b * FC1_OUT + k];
        xv = xv > 0.f ? xv : expm1f(xv);
        acc += xv * w[k * 10 + wv];
    }
#pragma unroll
    for (int off = 32; off > 0; off >>= 1) acc += __shfl_down(acc, off);
    __shared__ float zs[10];
    if (lane == 0) {
        float z = acc + fc2b[wv];
        zs[wv] = z > 0.f ? z : expm1f(z);
    }
    __syncthreads();
    if (t < 10) {
        float m = -1e30f;
        for (int jj = 0; jj < 10; jj++) m = fmaxf(m, zs[jj]);
        float s = 0.f;
        for (int jj = 0; jj < 10; jj++) s += expf(zs[jj] - m);
        out[b * 10 + t] = zs[t] - m - logf(s);
    }
}

extern "C" void kernel_launch(void* const* d_in, const int* in_sizes, int n_in,
                              void* d_out, int out_size, void* d_ws, size_t ws_size,
                              hipStream_t stream) {
    const float* x     = (const float*)d_in[0];
    const float* ps0   = (const float*)d_in[1];
    const float* ps1   = (const float*)d_in[2];
    const float* W1    = (const float*)d_in[3];
    const float* root1 = (const float*)d_in[4];
    const float* b1    = (const float*)d_in[5];
    const float* W2    = (const float*)d_in[6];
    const float* root2 = (const float*)d_in[7];
    const float* b2v   = (const float*)d_in[8];
    const float* fc1w  = (const float*)d_in[9];
    const float* fc1b  = (const float*)d_in[10];
    const float* fc2w  = (const float*)d_in[11];
    const float* fc2b  = (const float*)d_in[12];
    const int*   ei0   = (const int*)d_in[13];
    const int*   ei1   = (const int*)d_in[14];

    float* ws = (float*)d_ws;
    int*   cnt1 = (int*)ws;                        //      78,400
    int*   cnt2 = (int*)(ws + 78400);              //      19,600
    // ---- memset boundary: 98,000 words ----
    int*   rec1 = (int*)(ws + 98000);              //   3,763,200 (N0*CAP)
    int*   rec2 = (int*)(ws + 3861200);            //     940,800 (N1*CAP)
    float* h1   = ws + 4802000;                    //   2,508,800
    float* p1   = ws + 7310800;                    //     627,200
    float* h2   = ws + 7938000;                    //   1,254,400
    unsigned short* p2b = (unsigned short*)(ws + 9192400);  // 351,232 us = 175,616 w
    float* z1p  = ws + 9368016;                    //     114,688 (2 x 112 x 512)
    unsigned short* w2t = (unsigned short*)(ws + 9482704);  // 53,248 us = 26,624 w
    unsigned short* wt1 = (unsigned short*)(ws + 9509328);  // 1,605,632 us = 802,816 w
    // high water: 10,312,144 words = 41.2 MB

    hipMemsetAsync(ws, 0, (size_t)98000 * sizeof(float), stream);

    bucket_both<<<(E0 + E1 + 255) / 256, 256, 0, stream>>>(ei0, ei1, cnt1, rec1, cnt2, rec2);
    w2t_prep<<<(64 * KEXT + 255) / 256, 256, 0, stream>>>(W2, root2, w2t);
    wt1_prep<<<dim3(49, 8), 256, 0, stream>>>(fc1w, wt1);
    conv1_fused<<<N0 / 64, 256, 0, stream>>>(x, ps0, ei0, cnt1, rec1,
                                             W1, root1, b1, h1);
    pool1<<<(N1 * C1 + 255) / 256, 256, 0, stream>>>(h1, p1);
    conv2_fused<<<N1 / 16, 256, 0, stream>>>(p1, ps1, ei1, cnt2, rec2,
                                             w2t, b2v, h2);
    pool2b<<<(112 * FC1_IN + 255) / 256, 256, 0, stream>>>(h2, p2b);
    gemm_fc1<<<dim3(8, 7, 2), 256, 0, stream>>>(p2b, wt1, z1p);
    fc2_lsm<<<BSZ, 640, 0, stream>>>(z1p, fc1b, fc2w, fc2b, (float*)d_out);
}